// Round 4
// baseline (83.865 us; speedup 1.0000x reference)
//
#include <hip/hip_runtime.h>
#include <hip/hip_fp8.h>

#define B_ROWS 4096
#define NTOT   8192
#define D0     256
#define D1     64
#define KDIM   320   // bytes per phi row (fp8)
#define NSB    128   // stats blocks (64 rows each)
#define NTILE  64    // 8192 / 128
#define NTRI   2080  // NTILE*(NTILE+1)/2

typedef __attribute__((ext_vector_type(4))) float f32x4;

// workspace layout (bytes)
#define OFF_GAM   0        // 4 floats
#define OFF_CNT   16       // int completion counter (+pad)
#define OFF_PQ0   32       // 128 floats: per-block sum x^2 (dim0)
#define OFF_PQ1   544      // 128 floats: per-block sum x^2 (dim1)
#define OFF_P0    1056     // 128*256 floats: colsum partials dim0
#define OFF_P1    132128   // 128*64 floats: colsum partials dim1
#define OFF_R     164896   // 8192 floats
#define OFF_BSUM  197664   // 2080 doubles
#define OFF_PHI   214304   // 8192*320 bytes (fp8), 16B aligned

__device__ __forceinline__ void load_lds16(const void* g, void* l) {
    __builtin_amdgcn_global_load_lds(
        (const __attribute__((address_space(1))) void*)g,
        (__attribute__((address_space(3))) void*)l, 16, 0, 0);
}

// ---------------- K1: fused stats (colsum partials + sum-of-squares) --------
// 128 blocks x 256 threads; block b covers rows b*64 .. b*64+63 (one pass).
__global__ __launch_bounds__(256) void k_stats(
    const float* __restrict__ s0, const float* __restrict__ s1,
    const float* __restrict__ t0, const float* __restrict__ t1,
    float* __restrict__ part0, float* __restrict__ part1,
    float* __restrict__ pq0, float* __restrict__ pq1) {
    __shared__ float sh0[4][256];
    __shared__ float sh1[4][64];
    __shared__ float shq[4][2];
    int t = threadIdx.x, wv = t >> 6, lane = t & 63;
    int rb = blockIdx.x * 64;
    int c4 = lane * 4;          // 4 cols of dim0 handled by this thread
    int rr = wv;                // row subgroup 0..3

    f32x4 cs = {0.f, 0.f, 0.f, 0.f};
    float q0 = 0.f;
    #pragma unroll 4
    for (int k = 0; k < 16; ++k) {
        int row = rb + rr + k * 4;
        const float* b0 = (row < B_ROWS) ? s0 + (size_t)row * D0 : t0 + (size_t)(row - B_ROWS) * D0;
        f32x4 v = *(const f32x4*)(b0 + c4);
        cs.x += v.x; cs.y += v.y; cs.z += v.z; cs.w += v.w;
        q0 += v.x * v.x + v.y * v.y + v.z * v.z + v.w * v.w;
    }
    *(f32x4*)&sh0[rr][c4] = cs;

    float cs1 = 0.f, q1 = 0.f;
    #pragma unroll 4
    for (int k = 0; k < 16; ++k) {
        int row = rb + rr + k * 4;
        const float* b1 = (row < B_ROWS) ? s1 + (size_t)row * D1 : t1 + (size_t)(row - B_ROWS) * D1;
        float v = b1[lane];
        cs1 += v; q1 += v * v;
    }
    sh1[rr][lane] = cs1;

    #pragma unroll
    for (int o = 32; o; o >>= 1) { q0 += __shfl_xor(q0, o, 64); q1 += __shfl_xor(q1, o, 64); }
    if (lane == 0) { shq[wv][0] = q0; shq[wv][1] = q1; }
    __syncthreads();

    part0[blockIdx.x * D0 + t] = sh0[0][t] + sh0[1][t] + sh0[2][t] + sh0[3][t];
    if (t < D1) part1[blockIdx.x * D1 + t] = sh1[0][t] + sh1[1][t] + sh1[2][t] + sh1[3][t];
    if (t == 0) {
        pq0[blockIdx.x] = shq[0][0] + shq[1][0] + shq[2][0] + shq[3][0];
        pq1[blockIdx.x] = shq[0][1] + shq[1][1] + shq[2][1] + shq[3][1];
    }
}

// ---------------- K2: gamma (single block, fp64 reduce) + counter init ------
__global__ __launch_bounds__(256) void k_gamma(
    const float* __restrict__ pq0, const float* __restrict__ pq1,
    const float* __restrict__ part0, const float* __restrict__ part1,
    float* __restrict__ gam, int* __restrict__ counter) {
    __shared__ double sh[4][4];
    int t = threadIdx.x, wv = t >> 6, lane = t & 63;

    double a0 = 0.0, a1 = 0.0;
    if (t < NSB) { a0 = (double)pq0[t]; a1 = (double)pq1[t]; }

    double F0t = 0.0;
    for (int b = 0; b < NSB; ++b) F0t += (double)part0[b * D0 + t];
    double nf0 = F0t * F0t;

    double nf1 = 0.0;
    if (t < D1) {
        double F1t = 0.0;
        for (int b = 0; b < NSB; ++b) F1t += (double)part1[b * D1 + t];
        nf1 = F1t * F1t;
    }

    #pragma unroll
    for (int o = 32; o; o >>= 1) {
        a0  += __shfl_xor(a0, o, 64);
        a1  += __shfl_xor(a1, o, 64);
        nf0 += __shfl_xor(nf0, o, 64);
        nf1 += __shfl_xor(nf1, o, 64);
    }
    if (lane == 0) { sh[wv][0] = a0; sh[wv][1] = a1; sh[wv][2] = nf0; sh[wv][3] = nf1; }
    __syncthreads();
    if (t == 0) {
        double b0 = 0, b1 = 0, b2 = 0, b3 = 0;
        for (int w = 0; w < 4; ++w) { b0 += sh[w][0]; b1 += sh[w][1]; b2 += sh[w][2]; b3 += sh[w][3]; }
        double n = (double)NTOT;
        double g0 = (n * n - n) / (2.0 * n * b0 - 2.0 * b2);
        double g1 = (n * n - n) / (2.0 * n * b1 - 2.0 * b3);
        gam[0] = (float)g0; gam[1] = (float)g1;
        gam[2] = (float)sqrt(g0); gam[3] = (float)sqrt(g1);
        counter[0] = 0;
    }
}

// ---------------- K3: pack scaled fp8 features + r from quantized -----------
__global__ __launch_bounds__(256) void k_pack(
    const float* __restrict__ s0, const float* __restrict__ s1,
    const float* __restrict__ t0, const float* __restrict__ t1,
    const float* __restrict__ gam, unsigned char* __restrict__ phi,
    float* __restrict__ rvec) {
    int wv = threadIdx.x >> 6, lane = threadIdx.x & 63;
    int row = blockIdx.x * 4 + wv;
    float sg0 = gam[2], sg1 = gam[3];
    const float* b0 = (row < B_ROWS) ? s0 + (size_t)row * D0 : t0 + (size_t)(row - B_ROWS) * D0;
    const float* b1 = (row < B_ROWS) ? s1 + (size_t)row * D1 : t1 + (size_t)(row - B_ROWS) * D1;
    unsigned char* pr = phi + (size_t)row * KDIM;
    f32x4 v = *(const f32x4*)(b0 + lane * 4);
    __hip_fp8_e4m3 q0(v.x * sg0), q1(v.y * sg0), q2(v.z * sg0), q3(v.w * sg0);
    unsigned int word = (unsigned int)q0.__x | ((unsigned int)q1.__x << 8) |
                        ((unsigned int)q2.__x << 16) | ((unsigned int)q3.__x << 24);
    *(unsigned int*)(pr + lane * 4) = word;
    float f0 = (float)q0, f1 = (float)q1, f2 = (float)q2, f3 = (float)q3;
    float p = f0 * f0 + f1 * f1 + f2 * f2 + f3 * f3;
    __hip_fp8_e4m3 qd(b1[lane] * sg1);
    pr[D0 + lane] = qd.__x;
    float fd = (float)qd;
    p += fd * fd;
    #pragma unroll
    for (int o = 32; o; o >>= 1) p += __shfl_xor(p, o, 64);
    if (lane == 0) rvec[row] = p;   // r_i = ||phi_hat_i||^2 (exact wrt quantized)
}

// ---------------- K4: fused Gram+exp+reduce + last-block finalize ------------
// 128x128 tile, 4 waves (64x64 each), BK=64 fp8-elems, K=320, upper-tri grid.
__global__ __launch_bounds__(256) void k_mmd(
    const unsigned char* __restrict__ phi, const float* __restrict__ rvec,
    double* __restrict__ blocksum, int* __restrict__ counter,
    float* __restrict__ out) {
    // triangular decode: block t -> (I,J), I<=J
    int t = blockIdx.x;
    int I = (int)((129.0f - sqrtf(16641.0f - 8.0f * (float)t)) * 0.5f);
    while ((129 * I - I * I) / 2 > t) --I;
    while ((129 * (I + 1) - (I + 1) * (I + 1)) / 2 <= t) ++I;
    int J = I + (t - (129 * I - I * I) / 2);

    __shared__ unsigned char As[2][8192];
    __shared__ unsigned char Bs[2][8192];
    __shared__ float rIl[128], rJl[128];
    __shared__ float wsum[4];
    __shared__ int isLast;
    __shared__ double shd[4];

    int tid = threadIdx.x, wv = tid >> 6, lane = tid & 63;
    int wr = wv >> 1, wc = wv & 1;
    int rgrp = lane >> 4, rlow = lane & 15;
    const int rowA = I * 128, rowB = J * 128;

    if (tid < 128) rIl[tid] = rvec[rowA + tid];
    else           rJl[tid - 128] = rvec[rowB + (tid - 128)];

    // staging: LDS slot16 u at row r holds global col16 (u ^ ((r>>1)&3))
    int su = tid & 3;
    int sr0 = tid >> 2;      // 0..63
    #define STAGE(b, ks)                                                        \
        _Pragma("unroll")                                                       \
        for (int p = 0; p < 2; ++p) {                                           \
            int r = p * 64 + sr0;                                               \
            int gc = (ks) * 64 + ((su ^ ((r >> 1) & 3)) << 4);                  \
            load_lds16(phi + (size_t)(rowA + r) * KDIM + gc,                    \
                       &As[b][p * 4096 + wv * 1024]);                           \
            load_lds16(phi + (size_t)(rowB + r) * KDIM + gc,                    \
                       &Bs[b][p * 4096 + wv * 1024]);                           \
        }

    f32x4 acc_[4][4] = {};

    STAGE(0, 0);
    __syncthreads();

    int cur = 0;
    for (int ks = 0; ks < 5; ++ks) {
        if (ks < 4) { STAGE(cur ^ 1, ks + 1); }

        long af[4][2], bf[4][2];
        #pragma unroll
        for (int m = 0; m < 4; ++m) {
            int row = wr * 64 + m * 16 + rlow;
            #pragma unroll
            for (int kk = 0; kk < 2; ++kk) {
                int s16 = kk * 2 + (rgrp >> 1);
                int addr = row * 64 + ((s16 ^ ((row >> 1) & 3)) << 4) + (rgrp & 1) * 8;
                af[m][kk] = *(const long*)&As[cur][addr];
            }
        }
        #pragma unroll
        for (int n = 0; n < 4; ++n) {
            int col = wc * 64 + n * 16 + rlow;
            #pragma unroll
            for (int kk = 0; kk < 2; ++kk) {
                int s16 = kk * 2 + (rgrp >> 1);
                int addr = col * 64 + ((s16 ^ ((col >> 1) & 3)) << 4) + (rgrp & 1) * 8;
                bf[n][kk] = *(const long*)&Bs[cur][addr];
            }
        }
        #pragma unroll
        for (int m = 0; m < 4; ++m)
            #pragma unroll
            for (int n = 0; n < 4; ++n)
                #pragma unroll
                for (int kk = 0; kk < 2; ++kk)
                    acc_[m][n] = __builtin_amdgcn_mfma_f32_16x16x32_fp8_fp8(
                        af[m][kk], bf[n][kk], acc_[m][n], 0, 0, 0);
        __syncthreads();
        cur ^= 1;
    }

    // epilogue: K_ij = exp(2*dot - r_i - r_j) = exp(-||phi_i - phi_j||^2)
    float psum = 0.f;
    #pragma unroll
    for (int m = 0; m < 4; ++m) {
        float ri[4];
        #pragma unroll
        for (int j = 0; j < 4; ++j) ri[j] = rIl[wr * 64 + m * 16 + rgrp * 4 + j];
        #pragma unroll
        for (int n = 0; n < 4; ++n) {
            float rj = rJl[wc * 64 + n * 16 + rlow];
            f32x4 a = acc_[m][n];
            psum += __expf(2.f * a.x - ri[0] - rj);
            psum += __expf(2.f * a.y - ri[1] - rj);
            psum += __expf(2.f * a.z - ri[2] - rj);
            psum += __expf(2.f * a.w - ri[3] - rj);
        }
    }
    #pragma unroll
    for (int o = 32; o; o >>= 1) psum += __shfl_xor(psum, o, 64);
    if (lane == 0) wsum[wv] = psum;
    __syncthreads();
    if (tid == 0) {
        float bs = wsum[0] + wsum[1] + wsum[2] + wsum[3];
        double sgn = ((I < 32) == (J < 32)) ? 1.0 : -1.0;
        double fac = (I == J) ? 1.0 : 2.0;
        blocksum[blockIdx.x] = sgn * fac * (double)bs;
        __threadfence();                      // make blocksum device-visible
        int old = atomicAdd(counter, 1);      // device-scope
        isLast = (old == NTRI - 1);
    }
    __syncthreads();
    if (isLast) {
        __threadfence();                      // acquire other blocks' writes
        double s = 0.0;
        for (int i = tid; i < NTRI; i += 256) s += blocksum[i];
        #pragma unroll
        for (int o = 32; o; o >>= 1) s += __shfl_xor(s, o, 64);
        if (lane == 0) shd[wv] = s;
        __syncthreads();
        if (tid == 0)
            out[0] = (float)((shd[0] + shd[1] + shd[2] + shd[3]) /
                             ((double)B_ROWS * (double)B_ROWS));
    }
}

extern "C" void kernel_launch(void* const* d_in, const int* in_sizes, int n_in,
                              void* d_out, int out_size, void* d_ws, size_t ws_size,
                              hipStream_t stream) {
    const float* s0 = (const float*)d_in[0];
    const float* s1 = (const float*)d_in[1];
    const float* t0 = (const float*)d_in[2];
    const float* t1 = (const float*)d_in[3];
    char* ws = (char*)d_ws;
    float*  gam  = (float*)(ws + OFF_GAM);
    int*    cnt  = (int*)(ws + OFF_CNT);
    float*  pq0  = (float*)(ws + OFF_PQ0);
    float*  pq1  = (float*)(ws + OFF_PQ1);
    float*  p0   = (float*)(ws + OFF_P0);
    float*  p1   = (float*)(ws + OFF_P1);
    float*  rvec = (float*)(ws + OFF_R);
    double* bsum = (double*)(ws + OFF_BSUM);
    unsigned char* phi = (unsigned char*)(ws + OFF_PHI);

    k_stats<<<NSB, 256, 0, stream>>>(s0, s1, t0, t1, p0, p1, pq0, pq1);
    k_gamma<<<1, 256, 0, stream>>>(pq0, pq1, p0, p1, gam, cnt);
    k_pack<<<2048, 256, 0, stream>>>(s0, s1, t0, t1, gam, phi, rvec);
    k_mmd<<<NTRI, 256, 0, stream>>>(phi, rvec, bsum, cnt, (float*)d_out);
}

// Round 5
// 49.725 us; speedup vs baseline: 1.6866x; 1.6866x over previous
//
#include <hip/hip_runtime.h>
#include <hip/hip_fp8.h>

#define B_ROWS 4096
#define NTOT   8192
#define D0     256
#define D1     64
#define KDIM   320   // bytes per phi row (fp8, repacked order)
#define NSB    128   // stats blocks (64 rows each)
#define NTILE  64    // 8192 / 128
#define NTRI   2080  // NTILE*(NTILE+1)/2

typedef __attribute__((ext_vector_type(4))) float f32x4;
typedef __attribute__((ext_vector_type(2))) long long2v;

// workspace layout (bytes)
#define OFF_GAM   0        // 4 floats
#define OFF_PQ0   32       // 128 floats: per-block sum x^2 (dim0)
#define OFF_PQ1   544      // 128 floats: per-block sum x^2 (dim1)
#define OFF_P0    1056     // 128*256 floats: colsum partials dim0
#define OFF_P1    132128   // 128*64 floats: colsum partials dim1
#define OFF_R     164896   // 8192 floats
#define OFF_BSUM  197664   // 2080 doubles
#define OFF_PHI   214304   // 8192*320 bytes (fp8), 16B aligned

__device__ __forceinline__ void load_lds16(const void* g, void* l) {
    __builtin_amdgcn_global_load_lds(
        (const __attribute__((address_space(1))) void*)g,
        (__attribute__((address_space(3))) void*)l, 16, 0, 0);
}

// ---------------- K1: fused stats (colsum partials + sum-of-squares) --------
__global__ __launch_bounds__(256) void k_stats(
    const float* __restrict__ s0, const float* __restrict__ s1,
    const float* __restrict__ t0, const float* __restrict__ t1,
    float* __restrict__ part0, float* __restrict__ part1,
    float* __restrict__ pq0, float* __restrict__ pq1) {
    __shared__ float sh0[4][256];
    __shared__ float sh1[4][64];
    __shared__ float shq[4][2];
    int t = threadIdx.x, wv = t >> 6, lane = t & 63;
    int rb = blockIdx.x * 64;
    int c4 = lane * 4;
    int rr = wv;

    f32x4 cs = {0.f, 0.f, 0.f, 0.f};
    float q0 = 0.f;
    #pragma unroll 4
    for (int k = 0; k < 16; ++k) {
        int row = rb + rr + k * 4;
        const float* b0 = (row < B_ROWS) ? s0 + (size_t)row * D0 : t0 + (size_t)(row - B_ROWS) * D0;
        f32x4 v = *(const f32x4*)(b0 + c4);
        cs.x += v.x; cs.y += v.y; cs.z += v.z; cs.w += v.w;
        q0 += v.x * v.x + v.y * v.y + v.z * v.z + v.w * v.w;
    }
    *(f32x4*)&sh0[rr][c4] = cs;

    float cs1 = 0.f, q1 = 0.f;
    #pragma unroll 4
    for (int k = 0; k < 16; ++k) {
        int row = rb + rr + k * 4;
        const float* b1 = (row < B_ROWS) ? s1 + (size_t)row * D1 : t1 + (size_t)(row - B_ROWS) * D1;
        float v = b1[lane];
        cs1 += v; q1 += v * v;
    }
    sh1[rr][lane] = cs1;

    #pragma unroll
    for (int o = 32; o; o >>= 1) { q0 += __shfl_xor(q0, o, 64); q1 += __shfl_xor(q1, o, 64); }
    if (lane == 0) { shq[wv][0] = q0; shq[wv][1] = q1; }
    __syncthreads();

    part0[blockIdx.x * D0 + t] = sh0[0][t] + sh0[1][t] + sh0[2][t] + sh0[3][t];
    if (t < D1) part1[blockIdx.x * D1 + t] = sh1[0][t] + sh1[1][t] + sh1[2][t] + sh1[3][t];
    if (t == 0) {
        pq0[blockIdx.x] = shq[0][0] + shq[1][0] + shq[2][0] + shq[3][0];
        pq1[blockIdx.x] = shq[0][1] + shq[1][1] + shq[2][1] + shq[3][1];
    }
}

// ---------------- K2: gamma (single block, fp64 reduce) ----------------------
__global__ __launch_bounds__(256) void k_gamma(
    const float* __restrict__ pq0, const float* __restrict__ pq1,
    const float* __restrict__ part0, const float* __restrict__ part1,
    float* __restrict__ gam) {
    __shared__ double sh[4][4];
    int t = threadIdx.x, wv = t >> 6, lane = t & 63;

    double a0 = 0.0, a1 = 0.0;
    if (t < NSB) { a0 = (double)pq0[t]; a1 = (double)pq1[t]; }

    double F0t = 0.0;
    for (int b = 0; b < NSB; ++b) F0t += (double)part0[b * D0 + t];
    double nf0 = F0t * F0t;

    double nf1 = 0.0;
    if (t < D1) {
        double F1t = 0.0;
        for (int b = 0; b < NSB; ++b) F1t += (double)part1[b * D1 + t];
        nf1 = F1t * F1t;
    }

    #pragma unroll
    for (int o = 32; o; o >>= 1) {
        a0  += __shfl_xor(a0, o, 64);
        a1  += __shfl_xor(a1, o, 64);
        nf0 += __shfl_xor(nf0, o, 64);
        nf1 += __shfl_xor(nf1, o, 64);
    }
    if (lane == 0) { sh[wv][0] = a0; sh[wv][1] = a1; sh[wv][2] = nf0; sh[wv][3] = nf1; }
    __syncthreads();
    if (t == 0) {
        double b0 = 0, b1 = 0, b2 = 0, b3 = 0;
        for (int w = 0; w < 4; ++w) { b0 += sh[w][0]; b1 += sh[w][1]; b2 += sh[w][2]; b3 += sh[w][3]; }
        double n = (double)NTOT;
        double g0 = (n * n - n) / (2.0 * n * b0 - 2.0 * b2);
        double g1 = (n * n - n) / (2.0 * n * b1 - 2.0 * b3);
        gam[0] = (float)g0; gam[1] = (float)g1;
        gam[2] = (float)sqrt(g0); gam[3] = (float)sqrt(g1);
    }
}

// ---------------- K3: pack scaled fp8 (REPACKED row order) + r ---------------
// Row byte order: orig k -> kk=k>>5, rg=(k>>3)&3, b=k&7
//                 new off = (kk>>1)*64 + rg*16 + (kk&1)*8 + b
// => 16B at [t*64 + rg*16] holds lane-rg's fragments for kk=2t and kk=2t+1.
__global__ __launch_bounds__(256) void k_pack(
    const float* __restrict__ s0, const float* __restrict__ s1,
    const float* __restrict__ t0, const float* __restrict__ t1,
    const float* __restrict__ gam, unsigned char* __restrict__ phi,
    float* __restrict__ rvec) {
    int wv = threadIdx.x >> 6, lane = threadIdx.x & 63;
    int row = blockIdx.x * 4 + wv;
    float sg0 = gam[2], sg1 = gam[3];
    const float* b0 = (row < B_ROWS) ? s0 + (size_t)row * D0 : t0 + (size_t)(row - B_ROWS) * D0;
    const float* b1 = (row < B_ROWS) ? s1 + (size_t)row * D1 : t1 + (size_t)(row - B_ROWS) * D1;
    unsigned char* pr = phi + (size_t)row * KDIM;
    f32x4 v = *(const f32x4*)(b0 + lane * 4);
    __hip_fp8_e4m3 q0(v.x * sg0), q1(v.y * sg0), q2(v.z * sg0), q3(v.w * sg0);
    unsigned int word = (unsigned int)q0.__x | ((unsigned int)q1.__x << 8) |
                        ((unsigned int)q2.__x << 16) | ((unsigned int)q3.__x << 24);
    // dim0: k = lane*4 .. +3  (kk=lane>>3, rg=(lane>>1)&3, b=(lane&1)*4)
    int doff0 = ((lane >> 4) << 6) + (((lane >> 1) & 3) << 4) +
                (((lane >> 3) & 1) << 3) + ((lane & 1) << 2);
    *(unsigned int*)(pr + doff0) = word;
    float f0 = (float)q0, f1 = (float)q1, f2 = (float)q2, f3 = (float)q3;
    float p = f0 * f0 + f1 * f1 + f2 * f2 + f3 * f3;
    // dim1: k = 256+lane (kk=8+(lane>>5), rg=(lane>>3)&3, b=lane&7)
    __hip_fp8_e4m3 qd(b1[lane] * sg1);
    int doff1 = 256 + (((lane >> 3) & 3) << 4) + (((lane >> 5) & 1) << 3) + (lane & 7);
    pr[doff1] = qd.__x;
    float fd = (float)qd;
    p += fd * fd;
    #pragma unroll
    for (int o = 32; o; o >>= 1) p += __shfl_xor(p, o, 64);
    if (lane == 0) rvec[row] = p;   // r_i = ||phi_hat_i||^2 (exact wrt quantized)
}

// ---------------- K4: fused Gram+exp+reduce ----------------------------------
// 128x128 tile, 4 waves (64x64 each), full K=320 in 2 chunks (t:0..2, t:3..4),
// single 48KB LDS, 3 barriers total, b128 paired-fragment reads.
__global__ __launch_bounds__(256, 3) void k_mmd(
    const unsigned char* __restrict__ phi, const float* __restrict__ rvec,
    double* __restrict__ blocksum) {
    int tb = blockIdx.x;
    int I = (int)((129.0f - sqrtf(16641.0f - 8.0f * (float)tb)) * 0.5f);
    while ((129 * I - I * I) / 2 > tb) --I;
    while ((129 * (I + 1) - (I + 1) * (I + 1)) / 2 <= tb) ++I;
    int J = I + (tb - (129 * I - I * I) / 2);

    __shared__ unsigned char As[24576];
    __shared__ unsigned char Bs[24576];
    __shared__ float rIl[128], rJl[128];
    __shared__ float wsum[4];

    int tid = threadIdx.x, wv = tid >> 6, lane = tid & 63;
    int wr = wv >> 1, wc = wv & 1;
    int rgrp = lane >> 4, rlow = lane & 15;
    const int rowA = I * 128, rowB = J * 128;

    if (tid < 128) rIl[tid] = rvec[rowA + tid];
    else           rJl[tid - 128] = rvec[rowB + (tid - 128)];

    f32x4 acc_[4][4] = {};

    // stage chunk [tbase, tbase+nt) of both panels; LDS slot idx (16B units):
    // t'*512 + row*4 + slot, slot = rg ^ ((row>>1)&3)
    #define STAGE(tbase, nt)                                                    \
        _Pragma("unroll")                                                       \
        for (int it = 0; it < (nt) * 2; ++it) {                                 \
            int idx = it * 256 + tid;                                           \
            int tt = idx >> 9, rs = idx & 511;                                  \
            int row = rs >> 2, slot = rs & 3;                                   \
            int rg = slot ^ ((row >> 1) & 3);                                   \
            size_t gcol = ((tbase) + tt) * 64 + rg * 16;                        \
            load_lds16(phi + (size_t)(rowA + row) * KDIM + gcol,                \
                       As + it * 4096 + wv * 1024);                             \
            load_lds16(phi + (size_t)(rowB + row) * KDIM + gcol,                \
                       Bs + it * 4096 + wv * 1024);                             \
        }

    #define COMPUTE(kkbase, nt)                                                 \
        _Pragma("unroll")                                                       \
        for (int tt = 0; tt < (nt); ++tt) {                                     \
            long2v af[4], bf[4];                                                \
            _Pragma("unroll")                                                   \
            for (int m = 0; m < 4; ++m) {                                       \
                int row = wr * 64 + m * 16 + rlow;                              \
                int slot = rgrp ^ ((row >> 1) & 3);                             \
                af[m] = *(const long2v*)&As[tt * 8192 + row * 64 + slot * 16];  \
            }                                                                   \
            _Pragma("unroll")                                                   \
            for (int n = 0; n < 4; ++n) {                                       \
                int col = wc * 64 + n * 16 + rlow;                              \
                int slot = rgrp ^ ((col >> 1) & 3);                             \
                bf[n] = *(const long2v*)&Bs[tt * 8192 + col * 64 + slot * 16];  \
            }                                                                   \
            _Pragma("unroll")                                                   \
            for (int m = 0; m < 4; ++m)                                         \
                _Pragma("unroll")                                               \
                for (int n = 0; n < 4; ++n) {                                   \
                    acc_[m][n] = __builtin_amdgcn_mfma_f32_16x16x32_fp8_fp8(    \
                        af[m][0], bf[n][0], acc_[m][n], 0, 0, 0);               \
                    acc_[m][n] = __builtin_amdgcn_mfma_f32_16x16x32_fp8_fp8(    \
                        af[m][1], bf[n][1], acc_[m][n], 0, 0, 0);               \
                }                                                               \
        }

    STAGE(0, 3);
    __syncthreads();
    COMPUTE(0, 3);
    __syncthreads();      // all reads of chunk0 done before overwrite
    STAGE(3, 2);
    __syncthreads();
    COMPUTE(6, 2);

    // epilogue: K_ij = exp(2*dot - r_i - r_j) = exp(-||phi_i - phi_j||^2)
    float psum = 0.f;
    #pragma unroll
    for (int m = 0; m < 4; ++m) {
        float ri[4];
        #pragma unroll
        for (int j = 0; j < 4; ++j) ri[j] = rIl[wr * 64 + m * 16 + rgrp * 4 + j];
        #pragma unroll
        for (int n = 0; n < 4; ++n) {
            float rj = rJl[wc * 64 + n * 16 + rlow];
            f32x4 a = acc_[m][n];
            psum += __expf(2.f * a.x - ri[0] - rj);
            psum += __expf(2.f * a.y - ri[1] - rj);
            psum += __expf(2.f * a.z - ri[2] - rj);
            psum += __expf(2.f * a.w - ri[3] - rj);
        }
    }
    #pragma unroll
    for (int o = 32; o; o >>= 1) psum += __shfl_xor(psum, o, 64);
    if (lane == 0) wsum[wv] = psum;
    __syncthreads();
    if (tid == 0) {
        float bs = wsum[0] + wsum[1] + wsum[2] + wsum[3];
        double sgn = ((I < 32) == (J < 32)) ? 1.0 : -1.0;
        double fac = (I == J) ? 1.0 : 2.0;
        blocksum[tb] = sgn * fac * (double)bs;
    }
}

// ---------------- K5: finalize (reduce 2080 block sums) ----------------------
__global__ __launch_bounds__(256) void k_final(
    const double* __restrict__ blocksum, float* __restrict__ out) {
    __shared__ double sh[4];
    int t = threadIdx.x, wv = t >> 6, lane = t & 63;
    double s = 0.0;
    for (int i = t; i < NTRI; i += 256) s += blocksum[i];
    #pragma unroll
    for (int o = 32; o; o >>= 1) s += __shfl_xor(s, o, 64);
    if (lane == 0) sh[wv] = s;
    __syncthreads();
    if (t == 0) {
        double tot = sh[0] + sh[1] + sh[2] + sh[3];
        out[0] = (float)(tot / ((double)B_ROWS * (double)B_ROWS));
    }
}

extern "C" void kernel_launch(void* const* d_in, const int* in_sizes, int n_in,
                              void* d_out, int out_size, void* d_ws, size_t ws_size,
                              hipStream_t stream) {
    const float* s0 = (const float*)d_in[0];
    const float* s1 = (const float*)d_in[1];
    const float* t0 = (const float*)d_in[2];
    const float* t1 = (const float*)d_in[3];
    char* ws = (char*)d_ws;
    float*  gam  = (float*)(ws + OFF_GAM);
    float*  pq0  = (float*)(ws + OFF_PQ0);
    float*  pq1  = (float*)(ws + OFF_PQ1);
    float*  p0   = (float*)(ws + OFF_P0);
    float*  p1   = (float*)(ws + OFF_P1);
    float*  rvec = (float*)(ws + OFF_R);
    double* bsum = (double*)(ws + OFF_BSUM);
    unsigned char* phi = (unsigned char*)(ws + OFF_PHI);

    k_stats<<<NSB, 256, 0, stream>>>(s0, s1, t0, t1, p0, p1, pq0, pq1);
    k_gamma<<<1, 256, 0, stream>>>(pq0, pq1, p0, p1, gam);
    k_pack<<<2048, 256, 0, stream>>>(s0, s1, t0, t1, gam, phi, rvec);
    k_mmd<<<NTRI, 256, 0, stream>>>(phi, rvec, bsum);
    k_final<<<1, 256, 0, stream>>>(bsum, (float*)d_out);
}